// Round 5
// baseline (1117.715 us; speedup 1.0000x reference)
//
#include <hip/hip_runtime.h>
#include <hip/hip_bf16.h>
#include <math.h>

#define H 64
#define F 18
#define BSC 32        // destination nodes per bucket (per-wave LDS replicas)
#define NBK_MAX 3456  // max buckets supported by count/place LDS histograms
#define EPB 8192      // edges per block in count/place passes

typedef _Float16 f16x8 __attribute__((ext_vector_type(8)));
typedef float f32x4 __attribute__((ext_vector_type(4)));

// ---------------------------------------------------------------- embed ----
__global__ __launch_bounds__(256) void embed_kernel(
    const float* __restrict__ nf, const float* __restrict__ W,
    const float* __restrict__ b, _Float16* __restrict__ xh, int N)
{
    int n = blockIdx.x * 256 + threadIdx.x;
    if (n >= N) return;
    float acc[H];
#pragma unroll
    for (int j = 0; j < H; ++j) acc[j] = b[j];
    const float* f = nf + (long)n * F;
#pragma unroll
    for (int i = 0; i < F; ++i) {
        float c = f[i];
        const float* w = W + i * H;
#pragma unroll
        for (int j = 0; j < H; ++j) acc[j] += c * w[j];
    }
    union { uint4 v[8]; _Float16 h[64]; } O;
#pragma unroll
    for (int j = 0; j < H; ++j) O.h[j] = (_Float16)fmaxf(acc[j], 0.f);
    uint4* xo = (uint4*)(xh + (size_t)n * H);
#pragma unroll
    for (int i = 0; i < 8; ++i) xo[i] = O.v[i];
}

// ------------------------------------------------- B-fragment prepack -----
__global__ __launch_bounds__(256) void packfrag_kernel(
    const float* __restrict__ mW1, const float* __restrict__ aW1,
    f16x8* __restrict__ msgB, f16x8* __restrict__ attB)
{
    int t = blockIdx.x * 256 + threadIdx.x;  // 0..3071
    if (t >= 3072) return;
    int lane = t & 63;
    int frag = t >> 6;            // 0..47
    int l = frag / 24, f = frag % 24;
    int quad = lane >> 4, l15 = lane & 15;
    f16x8 v;
    if (f < 16) {
        int nt = f >> 2, kk = f & 3;
        const float* W = mW1 + (size_t)l * 128 * 64;
#pragma unroll
        for (int j = 0; j < 8; ++j) {
            int k = kk * 32 + quad * 8 + j;
            v[j] = (_Float16)W[k * 64 + nt * 16 + l15];
        }
        msgB[((size_t)l * 16 + f) * 64 + lane] = v;
    } else {
        int f2 = f - 16;
        int nt = f2 >> 2, kk = f2 & 3;
        const float* W = aW1 + (size_t)l * 128 * 32;
#pragma unroll
        for (int j = 0; j < 8; ++j) {
            int k = kk * 32 + quad * 8 + j;
            v[j] = (_Float16)W[k * 32 + nt * 16 + l15];
        }
        attB[((size_t)l * 8 + f2) * 64 + lane] = v;
    }
}

// ---------------------------------------------- update-path precompute ----
__global__ __launch_bounds__(256) void prep_update_kernel(
    const float* __restrict__ mW2, const float* __restrict__ mb2,
    const float* __restrict__ uW1,
    float* __restrict__ M2U, float* __restrict__ mbu)
{
    int t = blockIdx.x * 256 + threadIdx.x;  // 0..8191
    if (t >= 2 * 64 * 64) return;
    int l = t >> 12, r = t & 4095;
    int i = r >> 6, j = r & 63;
    const float* W2 = mW2 + (size_t)l * 4096;
    const float* U1b = uW1 + (size_t)l * 8192 + 4096;  // rows 64..127
    float s = 0.f;
    for (int k = 0; k < 64; ++k) s += W2[i * 64 + k] * U1b[k * 64 + j];
    M2U[t] = s;
    if (i == 0) {
        float sb = 0.f;
        const float* b2 = mb2 + (size_t)l * 64;
        for (int k = 0; k < 64; ++k) sb += b2[k] * U1b[k * 64 + j];
        mbu[l * 64 + j] = sb;
    }
}

// aggN stored in TRUE feature order; g==1 not row-permuted.
__global__ __launch_bounds__(256) void packfrag_upd_kernel(
    const float* __restrict__ uW1, const float* __restrict__ M2U,
    const float* __restrict__ uW2, f16x8* __restrict__ updB)
{
    int t = blockIdx.x * 256 + threadIdx.x;  // 0..3071
    if (t >= 3072) return;
    int lane = t & 63;
    int frag = t >> 6;  // 0..47
    int l = frag / 24, f = frag % 24;
    int quad = lane >> 4, l15 = lane & 15;
    int g = f >> 3, ff = f & 7;
    int nt = ff >> 1, kk = ff & 1;
    const float* src;
    if (g == 0)      src = uW1 + (size_t)l * 8192;       // rows 0..63
    else if (g == 1) src = M2U + (size_t)l * 4096;
    else             src = uW2 + (size_t)l * 4096;
    f16x8 v;
#pragma unroll
    for (int j = 0; j < 8; ++j) {
        int k = kk * 32 + quad * 8 + j;
        v[j] = (_Float16)src[k * 64 + nt * 16 + l15];
    }
    updB[(size_t)frag * 64 + lane] = v;
}

// ----------------------------------------------- scan (2-level chain) -----
__global__ __launch_bounds__(256) void scan1_kernel(
    const int* __restrict__ deg, int* __restrict__ part,
    int* __restrict__ bsum, int N)
{
    __shared__ int lds[256];
    int t = threadIdx.x;
    int base = blockIdx.x * 1024 + t * 4;
    int v[4];
#pragma unroll
    for (int s = 0; s < 4; ++s) v[s] = (base + s < N) ? deg[base + s] : 0;
    int sum = v[0] + v[1] + v[2] + v[3];
    lds[t] = sum;
    __syncthreads();
    for (int off = 1; off < 256; off <<= 1) {
        int xv = (t >= off) ? lds[t - off] : 0;
        __syncthreads();
        lds[t] += xv;
        __syncthreads();
    }
    int excl = lds[t] - sum;
    if (t == 255) bsum[blockIdx.x] = lds[255];
    int p = excl;
#pragma unroll
    for (int s = 0; s < 4; ++s) {
        if (base + s < N) part[base + s] = p;
        p += v[s];
    }
}

__global__ __launch_bounds__(256) void scan3_kernel(
    int* __restrict__ part, const int* __restrict__ bsum, int N)
{
    int i = blockIdx.x * 256 + threadIdx.x;
    if (i >= N) return;
    part[i] = part[i] + bsum[i >> 10];
}

// ----------------------------------------- coarse bucket partition --------
__global__ __launch_bounds__(256) void count_bucket_kernel(
    const int* __restrict__ col, int* __restrict__ cnt,
    int E, int NB, int NBK)
{
    __shared__ int lc[NBK_MAX];
    int t = threadIdx.x;
    for (int i = t; i < NBK; i += 256) lc[i] = 0;
    __syncthreads();
    for (int s = 0; s < EPB / 256; ++s) {
        int e = blockIdx.x * EPB + s * 256 + t;
        if (e < E) atomicAdd(lc + (unsigned)col[e] / BSC, 1);
    }
    __syncthreads();
    for (int i = t; i < NBK; i += 256)
        cnt[(size_t)i * NB + blockIdx.x] = lc[i];
}

__global__ __launch_bounds__(256) void place_kernel(
    const int* __restrict__ row, const int* __restrict__ col,
    const float* __restrict__ ew, const int* __restrict__ off,
    int4* __restrict__ edata, int E, int NB, int NBK)
{
    __shared__ int lc[NBK_MAX];
    int t = threadIdx.x;
    for (int i = t; i < NBK; i += 256) lc[i] = 0;
    __syncthreads();
    for (int s = 0; s < EPB / 256; ++s) {
        int e = blockIdx.x * EPB + s * 256 + t;
        if (e < E) {
            int cv = col[e];
            int c = (unsigned)cv / BSC;
            int r = atomicAdd(lc + c, 1);
            int pos = off[(size_t)c * NB + blockIdx.x] + r;
            edata[pos] = make_int4(row[e], cv, __float_as_int(ew[e]), 0);
        }
    }
}

// ---------------------------------------------------------- fused edge ----
// R20: grouped dedup-merged LDS accumulate. R19b post-mortem: per-tile
// 10.8k cy == 64 latency-serialized ds_read->add->ds_write RMW chains
// (possible aliasing forces in-order). Fix: per 4-edge group, merge
// duplicate-node contributions IN REGISTERS (equality bools already
// computed for the norm dedup), issue the 4 ds_reads together (single
// waitcnt), then masked writes (skip later duplicates; wave-uniform
// branches). 16 chains/tile instead of 64.
__global__ __launch_bounds__(256) void edge_fused_kernel(
    const _Float16* __restrict__ xh,
    const int4* __restrict__ edata, const int* __restrict__ off,
    const f16x8* __restrict__ msgB,  // [16][64] this layer
    const f16x8* __restrict__ attB,  // [8][64]
    const float* __restrict__ b1, const float* __restrict__ ab1,
    const float* __restrict__ aW2, const float* __restrict__ ab2,
    _Float16* __restrict__ aggN, float* __restrict__ snorm,
    int N, int E, int NB, int NBK)
{
    __shared__ float acc[4][BSC][H];   // per-wave replicas
    __shared__ float fwa[4][BSC];
    int tid = threadIdx.x;
    int b = blockIdx.x;
    for (int i = tid; i < 4 * BSC * H / 4; i += 256)
        ((float4*)acc)[i] = make_float4(0.f, 0.f, 0.f, 0.f);
    for (int i = tid; i < 4 * BSC; i += 256) ((float*)fwa)[i] = 0.f;

    int base = off[(size_t)b * NB];
    int end  = (b + 1 < NBK) ? off[(size_t)(b + 1) * NB] : E;
    int ecnt = end - base;
    int nlo  = b * BSC;

    int wib = tid >> 6;
    int lane = tid & 63;
    int quad = lane >> 4, l15 = lane & 15;
    float* accw = &acc[wib][0][0];
    float* fwaw = &fwa[wib][0];

    f16x8 mb[4][4], ab[2][4];
#pragma unroll
    for (int nt = 0; nt < 4; ++nt)
#pragma unroll
        for (int kk = 0; kk < 4; ++kk)
            mb[nt][kk] = msgB[(nt * 4 + kk) * 64 + lane];
#pragma unroll
    for (int nt = 0; nt < 2; ++nt)
#pragma unroll
        for (int kk = 0; kk < 4; ++kk)
            ab[nt][kk] = attB[(nt * 4 + kk) * 64 + lane];

    float ab1v0 = ab1[l15], ab1v1 = ab1[16 + l15];
    float aw20 = aW2[l15], aw21 = aW2[16 + l15];
    float ab2v = ab2[0];
    float bm[4];
#pragma unroll
    for (int nt = 0; nt < 4; ++nt) bm[nt] = b1[nt * 16 + l15];

    int jsw = ((l15 & 3) << 2) | (l15 >> 2);   // 4x4 transpose of l15
    __syncthreads();   // LDS zero done before any accumulation

    int ntiles = (ecnt + 63) >> 6;

    // prefetch first tile's edata
    int4 edmy;
    if (wib < ntiles) {
        int eown = (wib << 6) + lane;
        edmy = edata[base + (eown < ecnt ? eown : ecnt - 1)];
    }

    for (int t = wib; t < ntiles; t += 4) {
        int wbase = t << 6;

        // ---- issue NEXT tile's edata load (hidden under this tile) ----
        int4 ednx;
        int tn = t + 4;
        if (tn < ntiles) {
            int eo = (tn << 6) + lane;
            ednx = edata[base + (eo < ecnt ? eo : ecnt - 1)];
        }

        // ---- prologue: load A for sub-tile 0 ----
        f16x8 Acur[4], Anxt[4];
        {
            int sA = jsw;
            int rowv = __shfl(edmy.x, sA);
            int colv = __shfl(edmy.y, sA);
            const f16x8* rowp = (const f16x8*)(xh + (size_t)rowv * H);
            const f16x8* colp = (const f16x8*)(xh + (size_t)colv * H);
            Acur[0] = rowp[quad];
            Acur[1] = rowp[4 + quad];
            Acur[2] = colp[quad];
            Acur[3] = colp[4 + quad];
        }

#pragma unroll
        for (int mt = 0; mt < 4; ++mt) {
            // ---- issue next sub-tile's loads first (overlap) ----
            if (mt < 3) {
                int sA = (mt + 1) * 16 + jsw;
                int rowv = __shfl(edmy.x, sA);
                int colv = __shfl(edmy.y, sA);
                const f16x8* rowp = (const f16x8*)(xh + (size_t)rowv * H);
                const f16x8* colp = (const f16x8*)(xh + (size_t)colv * H);
                Anxt[0] = rowp[quad];
                Anxt[1] = rowp[4 + quad];
                Anxt[2] = colp[quad];
                Anxt[3] = colp[4 + quad];
            }

            // ---- attention GEMM (bias in C-init) ----
            f32x4 ac0 = {ab1v0, ab1v0, ab1v0, ab1v0};
            f32x4 ac1 = {ab1v1, ab1v1, ab1v1, ab1v1};
#pragma unroll
            for (int kk = 0; kk < 4; ++kk) {
                ac0 = __builtin_amdgcn_mfma_f32_16x16x32_f16(Acur[kk], ab[0][kk], ac0, 0, 0, 0);
                ac1 = __builtin_amdgcn_mfma_f32_16x16x32_f16(Acur[kk], ab[1][kk], ac1, 0, 0, 0);
            }
            float p[4];
#pragma unroll
            for (int r = 0; r < 4; ++r)
                p[r] = fmaxf(ac0[r], 0.f) * aw20 + fmaxf(ac1[r], 0.f) * aw21;
#pragma unroll
            for (int o = 1; o < 16; o <<= 1) {
#pragma unroll
                for (int r = 0; r < 4; ++r) p[r] += __shfl_xor(p[r], o);
            }
            float fw[4];
#pragma unroll
            for (int r = 0; r < 4; ++r) {
                int sl = mt * 16 + r * 4 + quad;
                float ewv = (wbase + sl < ecnt)
                            ? __int_as_float(__shfl(edmy.z, sl)) : 0.f;
                fw[r] = ewv / (1.f + __expf(-(p[r] + ab2v)));
            }

            // ---- message GEMM (bias in C-init) ----
            f32x4 mc[4];
#pragma unroll
            for (int nt = 0; nt < 4; ++nt) {
                f32x4 cc = {bm[nt], bm[nt], bm[nt], bm[nt]};
#pragma unroll
                for (int kk = 0; kk < 4; ++kk)
                    cc = __builtin_amdgcn_mfma_f32_16x16x32_f16(Acur[kk], mb[nt][kk], cc, 0, 0, 0);
                mc[nt] = cc;
            }

            // ---- epilogue: grouped dedup-merged LDS accumulate ----
#pragma unroll
            for (int r = 0; r < 4; ++r) {
                int sl0 = mt * 16 + r * 4;
                int nl0 = __shfl(edmy.y, sl0 + 0) - nlo;
                int nl1 = __shfl(edmy.y, sl0 + 1) - nlo;
                int nl2 = __shfl(edmy.y, sl0 + 2) - nlo;
                int nl3 = __shfl(edmy.y, sl0 + 3) - nlo;

                // own-quad edge's message, scaled (invalid edges have fw=0)
                float mm0 = fmaxf(mc[0][r], 0.f) * fw[r];
                float mm1 = fmaxf(mc[1][r], 0.f) * fw[r];
                float mm2 = fmaxf(mc[2][r], 0.f) * fw[r];
                float mm3 = fmaxf(mc[3][r], 0.f) * fw[r];
                auto a01 = __builtin_amdgcn_cvt_pkrtz(mm0, mm1);
                auto a23 = __builtin_amdgcn_cvt_pkrtz(mm2, mm3);
                int pk01, pk23;
                __builtin_memcpy(&pk01, &a01, 4);
                __builtin_memcpy(&pk23, &a23, 4);

                int shn = (quad & 1) * 16;
                float v[4];
#pragma unroll
                for (int j = 0; j < 4; ++j) {
                    int s01 = __shfl(pk01, j * 16 + l15);
                    int s23 = __shfl(pk23, j * 16 + l15);
                    int sv = (quad < 2) ? s01 : s23;
                    union { unsigned short u; _Float16 h; } C;
                    C.u = (unsigned short)(((unsigned)sv) >> shn);
                    v[j] = (float)C.h;
                }

                // node-equality (wave-uniform)
                bool e10 = nl1 == nl0, e20 = nl2 == nl0, e21 = nl2 == nl1;
                bool e30 = nl3 == nl0, e31 = nl3 == nl1, e32 = nl3 == nl2;

                // merge duplicate nodes in-register
                float m0 = v[0] + (e10 ? v[1] : 0.f) + (e20 ? v[2] : 0.f)
                                + (e30 ? v[3] : 0.f);
                float m1 = v[1] + (e21 ? v[2] : 0.f) + (e31 ? v[3] : 0.f);
                float m2 = v[2] + (e32 ? v[3] : 0.f);
                float m3 = v[3];

                // batched reads (one latency), masked writes (skip dups)
                float* p0 = &accw[nl0 * H + lane];
                float* p1 = &accw[nl1 * H + lane];
                float* p2 = &accw[nl2 * H + lane];
                float* p3 = &accw[nl3 * H + lane];
                float r0 = *p0, r1 = *p1, r2 = *p2, r3 = *p3;
                *p0 = r0 + m0;
                if (!e10) *p1 = r1 + m1;
                if (!e20 && !e21) *p2 = r2 + m2;
                if (!e30 && !e31 && !e32) *p3 = r3 + m3;

                // ---- norm (sum fw): uniform cross-quad dedup, no atomics
                float fx1 = __shfl_xor(fw[r], 16);
                float fx2 = __shfl_xor(fw[r], 32);
                float fx3 = __shfl_xor(fw[r], 48);
                float fv = fw[r];
                bool alive;
                int nlw;
                if (quad == 0) {
                    fv += (e10 ? fx1 : 0.f) + (e20 ? fx2 : 0.f) + (e30 ? fx3 : 0.f);
                    alive = true; nlw = nl0;
                } else if (quad == 1) {
                    fv += (e21 ? fx3 : 0.f) + (e31 ? fx2 : 0.f);
                    alive = !e10; nlw = nl1;
                } else if (quad == 2) {
                    fv += (e32 ? fx1 : 0.f);
                    alive = !e20 && !e21; nlw = nl2;
                } else {
                    alive = !e30 && !e31 && !e32; nlw = nl3;
                }
                if (l15 == 0 && alive) fwaw[nlw] += fv;
            }

            if (mt < 3) {
#pragma unroll
                for (int i = 0; i < 4; ++i) Acur[i] = Anxt[i];
            }
        }

        if (tn < ntiles) edmy = ednx;
    }

    __syncthreads();
    // ---- finalize: reduce replicas, normalize, write aggN + snorm ----
    int nmax = N - nlo; if (nmax > BSC) nmax = BSC;
    for (int i = wib; i < nmax; i += 4) {
        float s = acc[0][i][lane] + acc[1][i][lane]
                + acc[2][i][lane] + acc[3][i][lane];
        float fws = fwa[0][i] + fwa[1][i] + fwa[2][i] + fwa[3][i];
        float inv = 1.f / fmaxf(fws, 1e-6f);
        aggN[(size_t)(nlo + i) * H + lane] = (_Float16)(s * inv);
        if (lane == 0) snorm[nlo + i] = fws * inv;
    }
}

// --------------------------------------------------------------- update ----
__global__ __launch_bounds__(256, 2) void update_mfma_kernel(
    _Float16* __restrict__ xh, const _Float16* __restrict__ agg,
    const float* __restrict__ snorm,
    const f16x8* __restrict__ Bfrag,  // [24][64] this layer
    const float* __restrict__ mbu,    // [64]
    const float* __restrict__ ub1, const float* __restrict__ ub2, int N)
{
    __shared__ __align__(16) _Float16 hlds[4][16 * 80];
    int wib = threadIdx.x >> 6;
    int lane = threadIdx.x & 63;
    int wid = (blockIdx.x * 256 + threadIdx.x) >> 6;
    int quad = lane >> 4, l15 = lane & 15;
    int nbase = wid * 64;
    if (nbase >= N) return;

    f16x8 Bu[8], Bm[8], Bw[8];
#pragma unroll
    for (int i = 0; i < 8; ++i) {
        Bu[i] = Bfrag[i * 64 + lane];
        Bm[i] = Bfrag[(8 + i) * 64 + lane];
        Bw[i] = Bfrag[(16 + i) * 64 + lane];
    }
    float mbuv[4], b1v[4], b2v[4];
#pragma unroll
    for (int nt = 0; nt < 4; ++nt) {
        mbuv[nt] = mbu[nt * 16 + l15];
        b1v[nt] = ub1[nt * 16 + l15];
        b2v[nt] = ub2[nt * 16 + l15];
    }

    for (int mt = 0; mt < 4; ++mt) {
        int na = nbase + mt * 16 + l15;
        if (na >= N) na = N - 1;
        const f16x8* xrow = (const f16x8*)(xh + (size_t)na * H);
        f16x8 Ax[2];
        Ax[0] = xrow[quad];
        Ax[1] = xrow[4 + quad];
        const f16x8* arow = (const f16x8*)(agg + (size_t)na * H);
        f16x8 Aa[2];
        Aa[0] = arow[quad];
        Aa[1] = arow[4 + quad];

        f32x4 Cx[4], Ca[4];
#pragma unroll
        for (int nt = 0; nt < 4; ++nt) {
            f32x4 cx = {0.f, 0.f, 0.f, 0.f}, ca = {0.f, 0.f, 0.f, 0.f};
#pragma unroll
            for (int kk = 0; kk < 2; ++kk) {
                cx = __builtin_amdgcn_mfma_f32_16x16x32_f16(Ax[kk], Bu[nt * 2 + kk], cx, 0, 0, 0);
                ca = __builtin_amdgcn_mfma_f32_16x16x32_f16(Aa[kk], Bm[nt * 2 + kk], ca, 0, 0, 0);
            }
            Cx[nt] = cx; Ca[nt] = ca;
        }

        int noder = nbase + mt * 16 + quad * 4;
        float sn_r[4];
#pragma unroll
        for (int r = 0; r < 4; ++r) {
            int ng = noder + r; if (ng >= N) ng = N - 1;
            sn_r[r] = snorm[ng];
        }

#pragma unroll
        for (int nt = 0; nt < 4; ++nt) {
#pragma unroll
            for (int r = 0; r < 4; ++r) {
                float hv = fmaxf(Cx[nt][r] + Ca[nt][r]
                                 + sn_r[r] * mbuv[nt] + b1v[nt], 0.f);
                hlds[wib][(quad * 4 + r) * 80 + nt * 16 + l15] = (_Float16)hv;
            }
        }
        __asm__ __volatile__("s_waitcnt lgkmcnt(0)" ::: "memory");
        f16x8 Ah[2];
        Ah[0] = *(const f16x8*)&hlds[wib][l15 * 80 + quad * 8];
        Ah[1] = *(const f16x8*)&hlds[wib][l15 * 80 + 32 + quad * 8];
        __asm__ __volatile__("s_waitcnt lgkmcnt(0)" ::: "memory");

        f32x4 C2[4];
#pragma unroll
        for (int nt = 0; nt < 4; ++nt) {
            f32x4 cc = {0.f, 0.f, 0.f, 0.f};
#pragma unroll
            for (int kk = 0; kk < 2; ++kk)
                cc = __builtin_amdgcn_mfma_f32_16x16x32_f16(Ah[kk], Bw[nt * 2 + kk], cc, 0, 0, 0);
            C2[nt] = cc;
        }

#pragma unroll
        for (int r = 0; r < 4; ++r) {
            int ng = noder + r;
            if (ng < N) {
#pragma unroll
                for (int nt = 0; nt < 4; ++nt) {
                    size_t idx = (size_t)ng * H + nt * 16 + l15;
                    float xo = (float)xh[idx];
                    xh[idx] = (_Float16)fmaxf(C2[nt][r] + b2v[nt] + xo, 0.f);
                }
            }
        }
    }
}

// ----------------------------------------------------------------- head ----
__global__ __launch_bounds__(256) void max_kernel(
    const _Float16* __restrict__ xh16, unsigned int* __restrict__ serp, int N)
{
    int j = threadIdx.x & (H - 1);
    int g = (blockIdx.x * 256 + threadIdx.x) >> 6;
    int stride = (gridDim.x * 256) >> 6;
    float m = 0.f;  // x >= 0 after relu
    for (int n = g; n < N; n += stride)
        m = fmaxf(m, (float)xh16[(size_t)n * H + j]);
    atomicMax(serp + j, __float_as_uint(m));
}

__global__ void head_kernel(const unsigned int* __restrict__ serp,
                            const float* __restrict__ hW,
                            const float* __restrict__ hb,
                            float* __restrict__ out)
{
    int j = threadIdx.x;  // 64 threads = 1 wave
    float v = __uint_as_float(serp[j]) * hW[j];
#pragma unroll
    for (int off = 32; off > 0; off >>= 1) v += __shfl_down(v, off);
    if (j == 0) out[0] = v + hb[0];
}

// --------------------------------------------------------------- launch ----
extern "C" void kernel_launch(void* const* d_in, const int* in_sizes, int n_in,
                              void* d_out, int out_size, void* d_ws, size_t ws_size,
                              hipStream_t stream)
{
    const float* nf  = (const float*)d_in[0];
    const int*   ei  = (const int*)d_in[1];
    const float* ew  = (const float*)d_in[2];
    const float* eW  = (const float*)d_in[3];
    const float* eb_ = (const float*)d_in[4];
    const float* mW1 = (const float*)d_in[5];
    const float* mb1 = (const float*)d_in[6];
    const float* mW2 = (const float*)d_in[7];
    const float* mb2 = (const float*)d_in[8];
    const float* aW1 = (const float*)d_in[9];
    const float* ab1 = (const float*)d_in[10];
    const float* aW2 = (const float*)d_in[11];
    const float* ab2 = (const float*)d_in[12];
    const float* uW1 = (const float*)d_in[13];
    const float* ub1 = (const float*)d_in[14];
    const float* uW2 = (const float*)d_in[15];
    const float* ub2 = (const float*)d_in[16];
    const float* hW  = (const float*)d_in[17];
    const float* hb  = (const float*)d_in[18];

    int N = in_sizes[0] / F;
    int E = in_sizes[2];
    const int* row = ei;
    const int* col = ei + E;

    size_t Nr = ((size_t)N + 3) & ~(size_t)3;
    size_t Er = ((size_t)E + 3) & ~(size_t)3;
    int NBK = (N + BSC - 1) / BSC;         // buckets (= fused-kernel grid)
    int NB  = (E + EPB - 1) / EPB;         // blocks in count/place passes
    size_t M = (size_t)NBK * NB;           // bucket-count array size
    size_t Mr = (M + 3) & ~(size_t)3;

    _Float16* xh   = (_Float16*)d_ws;                 // Nr*64 f16
    _Float16* aggN = xh + Nr * 64;                    // Nr*64 f16 (normalized)
    float* snorm   = (float*)(aggN + Nr * 64);        // Nr
    unsigned int* serp = (unsigned int*)(snorm + Nr); // 64
    int* bsumA     = (int*)(serp + 64);               // 1024
    int* bsumAs    = bsumA + 1024;                    // 1024
    int* bsumT     = bsumAs + 1024;                   // 4
    f16x8* msgB    = (f16x8*)(bsumT + 4);             // 2048 units
    f16x8* attB    = msgB + 2048;                     // 1024 units
    float* M2U     = (float*)(attB + 1024);           // 8192
    float* mbu     = M2U + 8192;                      // 128
    f16x8* updB    = (f16x8*)(mbu + 128);             // 3072 units
    int* cnt       = (int*)(updB + 3072);             // Mr
    int* off       = cnt + Mr;                        // Mr
    int4* edata    = (int4*)(off + Mr);               // Er int4

    int nb_n = (N + 255) / 256;
    int nbA = (int)((M + 1023) / 1024);               // level-A scan blocks (<=1024)

    count_bucket_kernel<<<NB, 256, 0, stream>>>(col, cnt, E, NB, NBK);
    scan1_kernel<<<nbA, 256, 0, stream>>>(cnt, off, bsumA, (int)M);
    scan1_kernel<<<1, 256, 0, stream>>>(bsumA, bsumAs, bsumT, nbA);
    scan3_kernel<<<(int)((M + 255) / 256), 256, 0, stream>>>(off, bsumAs, (int)M);
    place_kernel<<<NB, 256, 0, stream>>>(row, col, ew, off, edata, E, NB, NBK);

    packfrag_kernel<<<12, 256, 0, stream>>>(mW1, aW1, msgB, attB);
    prep_update_kernel<<<32, 256, 0, stream>>>(mW2, mb2, uW1, M2U, mbu);
    packfrag_upd_kernel<<<12, 256, 0, stream>>>(uW1, M2U, uW2, updB);
    embed_kernel<<<nb_n, 256, 0, stream>>>(nf, eW, eb_, xh, N);

    int nwaves_n = (N + 63) / 64;
    for (int l = 0; l < 2; ++l) {
        edge_fused_kernel<<<NBK, 256, 0, stream>>>(
            xh, edata, off,
            msgB + (size_t)l * 16 * 64,
            attB + (size_t)l * 8 * 64,
            mb1 + (size_t)l * H,
            ab1 + (size_t)l * (H / 2),
            aW2 + (size_t)l * (H / 2), ab2 + (size_t)l,
            aggN, snorm, N, E, NB, NBK);
        update_mfma_kernel<<<(nwaves_n + 3) / 4, 256, 0, stream>>>(
            xh, aggN, snorm,
            updB + (size_t)l * 24 * 64,
            mbu + (size_t)l * 64,
            ub1 + (size_t)l * H, ub2 + (size_t)l * H, N);
    }

    hipMemsetAsync(serp, 0, 64 * sizeof(unsigned int), stream);
    max_kernel<<<256, 256, 0, stream>>>(xh, serp, N);
    head_kernel<<<1, 64, 0, stream>>>(serp, hW, hb, (float*)d_out);
}

// Round 6
// 538.964 us; speedup vs baseline: 2.0738x; 2.0738x over previous
//
#include <hip/hip_runtime.h>
#include <hip/hip_bf16.h>
#include <math.h>

#define H 64
#define F 18
#define NPW 8   // nodes per wave in edge_gather

typedef _Float16 f16x8 __attribute__((ext_vector_type(8)));
typedef _Float16 f16x4 __attribute__((ext_vector_type(4)));
typedef float f32x4 __attribute__((ext_vector_type(4)));

// ---------------------------------------------------------------- embed ----
__global__ __launch_bounds__(256) void embed_kernel(
    const float* __restrict__ nf, const float* __restrict__ W,
    const float* __restrict__ b, _Float16* __restrict__ xh, int N)
{
    int n = blockIdx.x * 256 + threadIdx.x;
    if (n >= N) return;
    float acc[H];
#pragma unroll
    for (int j = 0; j < H; ++j) acc[j] = b[j];
    const float* f = nf + (long)n * F;
#pragma unroll
    for (int i = 0; i < F; ++i) {
        float c = f[i];
        const float* w = W + i * H;
#pragma unroll
        for (int j = 0; j < H; ++j) acc[j] += c * w[j];
    }
    union { uint4 v[8]; _Float16 h[64]; } O;
#pragma unroll
    for (int j = 0; j < H; ++j) O.h[j] = (_Float16)fmaxf(acc[j], 0.f);
    uint4* xo = (uint4*)(xh + (size_t)n * H);
#pragma unroll
    for (int i = 0; i < 8; ++i) xo[i] = O.v[i];
}

// -------------------------------------------- UV B-fragment prepack -------
// W1 split: U-side = rows 0..63 of [mW1 | aW1] (cols 0..63 msg, 64..95 att),
// V-side = rows 64..127. Frag (l, side, nt 0..5, kk 0..1), MFMA 16x16x32
// B-layout: v[j] = W[k][col], k = side*64 + kk*32 + quad*8 + j,
// col = nt*16 + l15.
__global__ __launch_bounds__(256) void packfrag_uv_kernel(
    const float* __restrict__ mW1, const float* __restrict__ aW1,
    f16x8* __restrict__ uvB)
{
    int t = blockIdx.x * 256 + threadIdx.x;  // 0..3071
    if (t >= 3072) return;
    int lane = t & 63;
    int frag = t >> 6;             // 0..47
    int l = frag / 24, rem = frag % 24;
    int side = rem / 12, q = rem % 12;
    int nt = q >> 1, kk = q & 1;
    int quad = lane >> 4, l15 = lane & 15;
    int col = nt * 16 + l15;
    f16x8 v;
#pragma unroll
    for (int j = 0; j < 8; ++j) {
        int k = side * 64 + kk * 32 + quad * 8 + j;
        float w = (col < 64) ? mW1[(size_t)l * 8192 + k * 64 + col]
                             : aW1[(size_t)l * 4096 + k * 32 + (col - 64)];
        v[j] = (_Float16)w;
    }
    uvB[(size_t)frag * 64 + lane] = v;
}

// ---------------------------------------------- update-path precompute ----
__global__ __launch_bounds__(256) void prep_update_kernel(
    const float* __restrict__ mW2, const float* __restrict__ mb2,
    const float* __restrict__ uW1,
    float* __restrict__ M2U, float* __restrict__ mbu)
{
    int t = blockIdx.x * 256 + threadIdx.x;  // 0..8191
    if (t >= 2 * 64 * 64) return;
    int l = t >> 12, r = t & 4095;
    int i = r >> 6, j = r & 63;
    const float* W2 = mW2 + (size_t)l * 4096;
    const float* U1b = uW1 + (size_t)l * 8192 + 4096;  // rows 64..127
    float s = 0.f;
    for (int k = 0; k < 64; ++k) s += W2[i * 64 + k] * U1b[k * 64 + j];
    M2U[t] = s;
    if (i == 0) {
        float sb = 0.f;
        const float* b2 = mb2 + (size_t)l * 64;
        for (int k = 0; k < 64; ++k) sb += b2[k] * U1b[k * 64 + j];
        mbu[l * 64 + j] = sb;
    }
}

// aggN stored in TRUE feature order.
__global__ __launch_bounds__(256) void packfrag_upd_kernel(
    const float* __restrict__ uW1, const float* __restrict__ M2U,
    const float* __restrict__ uW2, f16x8* __restrict__ updB)
{
    int t = blockIdx.x * 256 + threadIdx.x;  // 0..3071
    if (t >= 3072) return;
    int lane = t & 63;
    int frag = t >> 6;  // 0..47
    int l = frag / 24, f = frag % 24;
    int quad = lane >> 4, l15 = lane & 15;
    int g = f >> 3, ff = f & 7;
    int nt = ff >> 1, kk = ff & 1;
    const float* src;
    if (g == 0)      src = uW1 + (size_t)l * 8192;       // rows 0..63
    else if (g == 1) src = M2U + (size_t)l * 4096;
    else             src = uW2 + (size_t)l * 4096;
    f16x8 v;
#pragma unroll
    for (int j = 0; j < 8; ++j) {
        int k = kk * 32 + quad * 8 + j;
        v[j] = (_Float16)src[k * 64 + nt * 16 + l15];
    }
    updB[(size_t)frag * 64 + lane] = v;
}

// ----------------------------------------------- scan -----------
__global__ __launch_bounds__(256) void scan1_kernel(
    const int* __restrict__ deg, int* __restrict__ part,
    int* __restrict__ bsum, int N)
{
    __shared__ int lds[256];
    int t = threadIdx.x;
    int base = blockIdx.x * 1024 + t * 4;
    int v[4];
#pragma unroll
    for (int s = 0; s < 4; ++s) v[s] = (base + s < N) ? deg[base + s] : 0;
    int sum = v[0] + v[1] + v[2] + v[3];
    lds[t] = sum;
    __syncthreads();
    for (int off = 1; off < 256; off <<= 1) {
        int xv = (t >= off) ? lds[t - off] : 0;
        __syncthreads();
        lds[t] += xv;
        __syncthreads();
    }
    int excl = lds[t] - sum;
    if (t == 255) bsum[blockIdx.x] = lds[255];
    int p = excl;
#pragma unroll
    for (int s = 0; s < 4; ++s) {
        if (base + s < N) part[base + s] = p;
        p += v[s];
    }
}

__global__ __launch_bounds__(256) void scan2_kernel(int* __restrict__ bsum, int nb)
{
    __shared__ int lds[256];
    int t = threadIdx.x;
    int v = (t < nb) ? bsum[t] : 0;
    lds[t] = v;
    __syncthreads();
    for (int off = 1; off < 256; off <<= 1) {
        int xv = (t >= off) ? lds[t - off] : 0;
        __syncthreads();
        lds[t] += xv;
        __syncthreads();
    }
    if (t < nb) bsum[t] = lds[t] - v;
}

__global__ __launch_bounds__(256) void scan3b_kernel(
    int* __restrict__ part, const int* __restrict__ bsum,
    int* __restrict__ cursor, int N)
{
    int i = blockIdx.x * 256 + threadIdx.x;
    if (i >= N) return;
    int v = part[i] + bsum[i >> 10];
    part[i] = v;
    cursor[i] = v;
}

// ----------------------------------------------------- CSR build ----------
__global__ __launch_bounds__(256) void hist_kernel(
    const int* __restrict__ col, int* __restrict__ deg, int E)
{
    int e = blockIdx.x * 256 + threadIdx.x;
    if (e < E) atomicAdd(deg + col[e], 1);
}

__global__ __launch_bounds__(256) void place_csr_kernel(
    const int* __restrict__ row, const int* __restrict__ col,
    const float* __restrict__ ew, int* __restrict__ cursor,
    int2* __restrict__ edata, int E)
{
    int e = blockIdx.x * 256 + threadIdx.x;
    if (e < E) {
        int c = col[e];
        int pos = atomicAdd(cursor + c, 1);
        edata[pos] = make_int2(row[e], __float_as_int(ew[e]));
    }
}

// -------------------------------------------------- per-node U/V GEMM -----
// out[n][96] = xh[n]·W1side (+bias for U side). A-layout identical to
// update_mfma; B from packfrag_uv.
__global__ __launch_bounds__(256) void uv_mfma_kernel(
    const _Float16* __restrict__ xh, const f16x8* __restrict__ Bf,
    const float* __restrict__ mb1, const float* __restrict__ ab1,
    _Float16* __restrict__ out, int N, int side)
{
    int lane = threadIdx.x & 63;
    int wid = (blockIdx.x * 256 + threadIdx.x) >> 6;
    int quad = lane >> 4, l15 = lane & 15;
    int nbase = wid * 64;
    if (nbase >= N) return;

    f16x8 B[12];
#pragma unroll
    for (int i = 0; i < 12; ++i) B[i] = Bf[i * 64 + lane];
    float bv[6];
#pragma unroll
    for (int nt = 0; nt < 6; ++nt) {
        int col = nt * 16 + l15;
        bv[nt] = side ? 0.f : (col < 64 ? mb1[col] : ab1[col - 64]);
    }

    for (int mt = 0; mt < 4; ++mt) {
        int na = nbase + mt * 16 + l15;
        if (na >= N) na = N - 1;
        const f16x8* xrow = (const f16x8*)(xh + (size_t)na * H);
        f16x8 Ax[2];
        Ax[0] = xrow[quad];
        Ax[1] = xrow[4 + quad];

        f32x4 C[6];
#pragma unroll
        for (int nt = 0; nt < 6; ++nt) {
            f32x4 cc = {bv[nt], bv[nt], bv[nt], bv[nt]};
#pragma unroll
            for (int kk = 0; kk < 2; ++kk)
                cc = __builtin_amdgcn_mfma_f32_16x16x32_f16(Ax[kk], B[nt * 2 + kk], cc, 0, 0, 0);
            C[nt] = cc;
        }
#pragma unroll
        for (int r = 0; r < 4; ++r) {
            int n = nbase + mt * 16 + quad * 4 + r;
            if (n < N) {
#pragma unroll
                for (int nt = 0; nt < 6; ++nt)
                    out[(size_t)n * 96 + nt * 16 + l15] = (_Float16)C[nt][r];
            }
        }
    }
}

// ---------------------------------------------------------- edge gather ---
// R21: per-edge work is pure VALU (no MFMA): h = relu(U[row] + V[col]),
// att = sigmoid(relu-dot). Edges CSR-sorted by destination; one wave owns
// NPW nodes; its 8 groups (8 lanes each) process 8 edges of the CURRENT
// node in parallel, accumulating sum(fw*h) in REGISTERS (slice s = 8
// features per lane). Node end: 3x shfl_xor cross-group reduce ->
// normalize -> direct aggN/snorm write. No LDS accumulator, no atomics,
// no hfw intermediate, no gather pass. V[col] loaded once per node.
__global__ __launch_bounds__(256) void edge_gather_kernel(
    const _Float16* __restrict__ Ur,   // [N][96]
    const _Float16* __restrict__ Vc,   // [N][96]
    const int2* __restrict__ edata,    // CSR-sorted {row, ew}
    const int* __restrict__ startp, const int* __restrict__ deg,
    const float* __restrict__ aW2, const float* __restrict__ ab2,
    _Float16* __restrict__ aggN, float* __restrict__ snorm, int N)
{
    int wid = (blockIdx.x * 256 + threadIdx.x) >> 6;
    int lane = threadIdx.x & 63;
    int g = lane >> 3, s = lane & 7;
    int n0 = wid * NPW;
    if (n0 >= N) return;
    int n1 = n0 + NPW; if (n1 > N) n1 = N;

    float aw2v[4];
#pragma unroll
    for (int j = 0; j < 4; ++j) aw2v[j] = aW2[s * 4 + j];
    float ab2v = ab2[0];

    for (int n = n0; n < n1; ++n) {
        int e0 = startp[n];
        int d = deg[n];
        const _Float16* vrow = Vc + (size_t)n * 96;
        f16x8 vm = *(const f16x8*)(vrow + s * 8);
        f16x4 va = *(const f16x4*)(vrow + 64 + s * 4);

        float acc[8];
#pragma unroll
        for (int j = 0; j < 8; ++j) acc[j] = 0.f;
        float rfw = 0.f;

        int iters = (d + 7) >> 3;
        for (int it = 0; it < iters; ++it) {
            int ei = it * 8 + g;
            bool valid = ei < d;
            int e = e0 + (valid ? ei : 0);
            int2 ed = edata[e];
            float ew = valid ? __int_as_float(ed.y) : 0.f;
            const _Float16* urow = Ur + (size_t)ed.x * 96;
            f16x8 um = *(const f16x8*)(urow + s * 8);
            f16x4 ua = *(const f16x4*)(urow + 64 + s * 4);

            // main h = relu(U+V), feature slice s*8..s*8+7
            _Float16 h[8];
#pragma unroll
            for (int j = 0; j < 8; ++j) {
                _Float16 z = um[j] + vm[j];
                h[j] = z > (_Float16)0 ? z : (_Float16)0;
            }
            // attention partial dot (4 att features per lane)
            float pp = 0.f;
#pragma unroll
            for (int j = 0; j < 4; ++j) {
                _Float16 za = ua[j] + va[j];
                float zf = (float)(za > (_Float16)0 ? za : (_Float16)0);
                pp += zf * aw2v[j];
            }
            pp += __shfl_xor(pp, 1);
            pp += __shfl_xor(pp, 2);
            pp += __shfl_xor(pp, 4);
            float fw = ew / (1.f + __expf(-(pp + ab2v)));
#pragma unroll
            for (int j = 0; j < 8; ++j) acc[j] += (float)h[j] * fw;
            rfw += fw;
        }

        // cross-group reduce (groups = lane bits 3..5)
#pragma unroll
        for (int o = 8; o <= 32; o <<= 1) {
#pragma unroll
            for (int j = 0; j < 8; ++j) acc[j] += __shfl_xor(acc[j], o);
            rfw += __shfl_xor(rfw, o);
        }
        float inv = 1.f / fmaxf(rfw, 1e-6f);
        if (g == 0) {
            union { _Float16 h[8]; uint4 v; } O;
#pragma unroll
            for (int j = 0; j < 8; ++j) O.h[j] = (_Float16)(acc[j] * inv);
            *(uint4*)(aggN + (size_t)n * H + s * 8) = O.v;
        }
        if (lane == 0) snorm[n] = rfw * inv;
    }
}

// --------------------------------------------------------------- update ----
__global__ __launch_bounds__(256, 2) void update_mfma_kernel(
    _Float16* __restrict__ xh, const _Float16* __restrict__ agg,
    const float* __restrict__ snorm,
    const f16x8* __restrict__ Bfrag,  // [24][64] this layer
    const float* __restrict__ mbu,    // [64]
    const float* __restrict__ ub1, const float* __restrict__ ub2, int N)
{
    __shared__ __align__(16) _Float16 hlds[4][16 * 80];
    int wib = threadIdx.x >> 6;
    int lane = threadIdx.x & 63;
    int wid = (blockIdx.x * 256 + threadIdx.x) >> 6;
    int quad = lane >> 4, l15 = lane & 15;
    int nbase = wid * 64;
    if (nbase >= N) return;

    f16x8 Bu[8], Bm[8], Bw[8];
#pragma unroll
    for (int i = 0; i < 8; ++i) {
        Bu[i] = Bfrag[i * 64 + lane];
        Bm[i] = Bfrag[(8 + i) * 64 + lane];
        Bw[i] = Bfrag[(16 + i) * 64 + lane];
    }
    float mbuv[4], b1v[4], b2v[4];
#pragma unroll
    for (int nt = 0; nt < 4; ++nt) {
        mbuv[nt] = mbu[nt * 16 + l15];
        b1v[nt] = ub1[nt * 16 + l15];
        b2v[nt] = ub2[nt * 16 + l15];
    }

    for (int mt = 0; mt < 4; ++mt) {
        int na = nbase + mt * 16 + l15;
        if (na >= N) na = N - 1;
        const f16x8* xrow = (const f16x8*)(xh + (size_t)na * H);
        f16x8 Ax[2];
        Ax[0] = xrow[quad];
        Ax[1] = xrow[4 + quad];
        const f16x8* arow = (const f16x8*)(agg + (size_t)na * H);
        f16x8 Aa[2];
        Aa[0] = arow[quad];
        Aa[1] = arow[4 + quad];

        f32x4 Cx[4], Ca[4];
#pragma unroll
        for (int nt = 0; nt < 4; ++nt) {
            f32x4 cx = {0.f, 0.f, 0.f, 0.f}, ca = {0.f, 0.f, 0.f, 0.f};
#pragma unroll
            for (int kk = 0; kk < 2; ++kk) {
                cx = __builtin_amdgcn_mfma_f32_16x16x32_f16(Ax[kk], Bu[nt * 2 + kk], cx, 0, 0, 0);
                ca = __builtin_amdgcn_mfma_f32_16x16x32_f16(Aa[kk], Bm[nt * 2 + kk], ca, 0, 0, 0);
            }
            Cx[nt] = cx; Ca[nt] = ca;
        }

        int noder = nbase + mt * 16 + quad * 4;
        float sn_r[4];
#pragma unroll
        for (int r = 0; r < 4; ++r) {
            int ng = noder + r; if (ng >= N) ng = N - 1;
            sn_r[r] = snorm[ng];
        }

#pragma unroll
        for (int nt = 0; nt < 4; ++nt) {
#pragma unroll
            for (int r = 0; r < 4; ++r) {
                float hv = fmaxf(Cx[nt][r] + Ca[nt][r]
                                 + sn_r[r] * mbuv[nt] + b1v[nt], 0.f);
                hlds[wib][(quad * 4 + r) * 80 + nt * 16 + l15] = (_Float16)hv;
            }
        }
        __asm__ __volatile__("s_waitcnt lgkmcnt(0)" ::: "memory");
        f16x8 Ah[2];
        Ah[0] = *(const f16x8*)&hlds[wib][l15 * 80 + quad * 8];
        Ah[1] = *(const f16x8*)&hlds[wib][l15 * 80 + 32 + quad * 8];
        __asm__ __volatile__("s_waitcnt lgkmcnt(0)" ::: "memory");

        f32x4 C2[4];
#pragma unroll
        for (int nt = 0; nt < 4; ++nt) {
            f32x4 cc = {0.f, 0.f, 0.f, 0.f};
#pragma unroll
            for (int kk = 0; kk < 2; ++kk)
                cc = __builtin_amdgcn_mfma_f32_16x16x32_f16(Ah[kk], Bw[nt * 2 + kk], cc, 0, 0, 0);
            C2[nt] = cc;
        }

#pragma unroll
        for (int r = 0; r < 4; ++r) {
            int ng = noder + r;
            if (ng < N) {
#pragma unroll
                for (int nt = 0; nt < 4; ++nt) {
                    size_t idx = (size_t)ng * H + nt * 16 + l15;
                    float xo = (float)xh[idx];
                    xh[idx] = (_Float16)fmaxf(C2[nt][r] + b2v[nt] + xo, 0.f);
                }
            }
        }
    }
}

// ----------------------------------------------------------------- head ----
__global__ __launch_bounds__(256) void max_kernel(
    const _Float16* __restrict__ xh16, unsigned int* __restrict__ serp, int N)
{
    int j = threadIdx.x & (H - 1);
    int g = (blockIdx.x * 256 + threadIdx.x) >> 6;
    int stride = (gridDim.x * 256) >> 6;
    float m = 0.f;  // x >= 0 after relu
    for (int n = g; n < N; n += stride)
        m = fmaxf(m, (float)xh16[(size_t)n * H + j]);
    atomicMax(serp + j, __float_as_uint(m));
}

__global__ void head_kernel(const unsigned int* __restrict__ serp,
                            const float* __restrict__ hW,
                            const float* __restrict__ hb,
                            float* __restrict__ out)
{
    int j = threadIdx.x;  // 64 threads = 1 wave
    float v = __uint_as_float(serp[j]) * hW[j];
#pragma unroll
    for (int off = 32; off > 0; off >>= 1) v += __shfl_down(v, off);
    if (j == 0) out[0] = v + hb[0];
}

// --------------------------------------------------------------- launch ----
extern "C" void kernel_launch(void* const* d_in, const int* in_sizes, int n_in,
                              void* d_out, int out_size, void* d_ws, size_t ws_size,
                              hipStream_t stream)
{
    const float* nf  = (const float*)d_in[0];
    const int*   ei  = (const int*)d_in[1];
    const float* ew  = (const float*)d_in[2];
    const float* eW  = (const float*)d_in[3];
    const float* eb_ = (const float*)d_in[4];
    const float* mW1 = (const float*)d_in[5];
    const float* mb1 = (const float*)d_in[6];
    const float* mW2 = (const float*)d_in[7];
    const float* mb2 = (const float*)d_in[8];
    const float* aW1 = (const float*)d_in[9];
    const float* ab1 = (const float*)d_in[10];
    const float* aW2 = (const float*)d_in[11];
    const float* ab2 = (const float*)d_in[12];
    const float* uW1 = (const float*)d_in[13];
    const float* ub1 = (const float*)d_in[14];
    const float* uW2 = (const float*)d_in[15];
    const float* ub2 = (const float*)d_in[16];
    const float* hW  = (const float*)d_in[17];
    const float* hb  = (const float*)d_in[18];

    int N = in_sizes[0] / F;
    int E = in_sizes[2];
    const int* row = ei;
    const int* col = ei + E;

    size_t Nr = ((size_t)N + 3) & ~(size_t)3;
    size_t Er = ((size_t)E + 3) & ~(size_t)3;

    _Float16* xh   = (_Float16*)d_ws;                 // Nr*64 f16
    _Float16* aggN = xh + Nr * 64;                    // Nr*64 f16
    float* snorm   = (float*)(aggN + Nr * 64);        // Nr
    unsigned int* serp = (unsigned int*)(snorm + Nr); // 64
    int* deg       = (int*)(serp + 64);               // Nr
    int* startp    = deg + Nr;                        // Nr
    int* cursor    = startp + Nr;                     // Nr
    int* bsum      = cursor + Nr;                     // 256
    float* M2U     = (float*)(bsum + 256);            // 8192
    float* mbu     = M2U + 8192;                      // 128
    f16x8* updB    = (f16x8*)(mbu + 128);             // 3072 units
    f16x8* uvB     = updB + 3072;                     // 3072 units
    _Float16* Ur   = (_Float16*)(uvB + 3072);         // Nr*96
    _Float16* Vc   = Ur + Nr * 96;                    // Nr*96
    int2* edata    = (int2*)(Vc + Nr * 96);           // Er

    int nb_n = (N + 255) / 256;
    int nb_e = (E + 255) / 256;
    int nb_scan = (N + 1023) / 1024;   // <=256

    hipMemsetAsync(deg, 0, (size_t)N * sizeof(int), stream);
    hist_kernel<<<nb_e, 256, 0, stream>>>(col, deg, E);
    scan1_kernel<<<nb_scan, 256, 0, stream>>>(deg, startp, bsum, N);
    scan2_kernel<<<1, 256, 0, stream>>>(bsum, nb_scan);
    scan3b_kernel<<<nb_n, 256, 0, stream>>>(startp, bsum, cursor, N);
    place_csr_kernel<<<nb_e, 256, 0, stream>>>(row, col, ew, cursor, edata, E);

    packfrag_uv_kernel<<<12, 256, 0, stream>>>(mW1, aW1, uvB);
    prep_update_kernel<<<32, 256, 0, stream>>>(mW2, mb2, uW1, M2U, mbu);
    packfrag_upd_kernel<<<12, 256, 0, stream>>>(uW1, M2U, uW2, updB);
    embed_kernel<<<nb_n, 256, 0, stream>>>(nf, eW, eb_, xh, N);

    int nwaves_n = (N + 63) / 64;
    int nb_uv = (N + 255) / 256;
    int nb_eg = (N + NPW * 4 - 1) / (NPW * 4);
    for (int l = 0; l < 2; ++l) {
        uv_mfma_kernel<<<nb_uv, 256, 0, stream>>>(
            xh, uvB + ((size_t)l * 2 + 0) * 12 * 64,
            mb1 + (size_t)l * H, ab1 + (size_t)l * (H / 2), Ur, N, 0);
        uv_mfma_kernel<<<nb_uv, 256, 0, stream>>>(
            xh, uvB + ((size_t)l * 2 + 1) * 12 * 64,
            mb1, ab1, Vc, N, 1);
        edge_gather_kernel<<<nb_eg, 256, 0, stream>>>(
            Ur, Vc, edata, startp, deg,
            aW2 + (size_t)l * (H / 2), ab2 + (size_t)l,
            aggN, snorm, N);
        update_mfma_kernel<<<(nwaves_n + 3) / 4, 256, 0, stream>>>(
            xh, aggN, snorm,
            updB + (size_t)l * 24 * 64,
            mbu + (size_t)l * 64,
            ub1 + (size_t)l * H, ub2 + (size_t)l * H, N);
    }

    hipMemsetAsync(serp, 0, 64 * sizeof(unsigned int), stream);
    max_kernel<<<256, 256, 0, stream>>>(xh, serp, N);
    head_kernel<<<1, 64, 0, stream>>>(serp, hW, hb, (float*)d_out);
}

// Round 7
// 415.704 us; speedup vs baseline: 2.6887x; 1.2965x over previous
//
#include <hip/hip_runtime.h>
#include <hip/hip_bf16.h>
#include <math.h>

#define H 64
#define F 18
#define NPW 8      // nodes per wave in edge_gather
#define NBKT 1024  // max coarse buckets (LDS array size)
#define EPB 8192   // edges per block in count/place passes

typedef _Float16 f16x8 __attribute__((ext_vector_type(8)));
typedef _Float16 f16x4 __attribute__((ext_vector_type(4)));
typedef float f32x4 __attribute__((ext_vector_type(4)));

// ---------------------------------------------------------------- embed ----
__global__ __launch_bounds__(256) void embed_kernel(
    const float* __restrict__ nf, const float* __restrict__ W,
    const float* __restrict__ b, _Float16* __restrict__ xh, int N)
{
    int n = blockIdx.x * 256 + threadIdx.x;
    if (n >= N) return;
    float acc[H];
#pragma unroll
    for (int j = 0; j < H; ++j) acc[j] = b[j];
    const float* f = nf + (long)n * F;
#pragma unroll
    for (int i = 0; i < F; ++i) {
        float c = f[i];
        const float* w = W + i * H;
#pragma unroll
        for (int j = 0; j < H; ++j) acc[j] += c * w[j];
    }
    union { uint4 v[8]; _Float16 h[64]; } O;
#pragma unroll
    for (int j = 0; j < H; ++j) O.h[j] = (_Float16)fmaxf(acc[j], 0.f);
    uint4* xo = (uint4*)(xh + (size_t)n * H);
#pragma unroll
    for (int i = 0; i < 8; ++i) xo[i] = O.v[i];
}

// -------------------------------------------- UV B-fragment prepack -------
__global__ __launch_bounds__(256) void packfrag_uv_kernel(
    const float* __restrict__ mW1, const float* __restrict__ aW1,
    f16x8* __restrict__ uvB)
{
    int t = blockIdx.x * 256 + threadIdx.x;  // 0..3071
    if (t >= 3072) return;
    int lane = t & 63;
    int frag = t >> 6;             // 0..47
    int l = frag / 24, rem = frag % 24;
    int side = rem / 12, q = rem % 12;
    int nt = q >> 1, kk = q & 1;
    int quad = lane >> 4, l15 = lane & 15;
    int col = nt * 16 + l15;
    f16x8 v;
#pragma unroll
    for (int j = 0; j < 8; ++j) {
        int k = side * 64 + kk * 32 + quad * 8 + j;
        float w = (col < 64) ? mW1[(size_t)l * 8192 + k * 64 + col]
                             : aW1[(size_t)l * 4096 + k * 32 + (col - 64)];
        v[j] = (_Float16)w;
    }
    uvB[(size_t)frag * 64 + lane] = v;
}

// ---------------------------------------------- update-path precompute ----
__global__ __launch_bounds__(256) void prep_update_kernel(
    const float* __restrict__ mW2, const float* __restrict__ mb2,
    const float* __restrict__ uW1,
    float* __restrict__ M2U, float* __restrict__ mbu)
{
    int t = blockIdx.x * 256 + threadIdx.x;  // 0..8191
    if (t >= 2 * 64 * 64) return;
    int l = t >> 12, r = t & 4095;
    int i = r >> 6, j = r & 63;
    const float* W2 = mW2 + (size_t)l * 4096;
    const float* U1b = uW1 + (size_t)l * 8192 + 4096;  // rows 64..127
    float s = 0.f;
    for (int k = 0; k < 64; ++k) s += W2[i * 64 + k] * U1b[k * 64 + j];
    M2U[t] = s;
    if (i == 0) {
        float sb = 0.f;
        const float* b2 = mb2 + (size_t)l * 64;
        for (int k = 0; k < 64; ++k) sb += b2[k] * U1b[k * 64 + j];
        mbu[l * 64 + j] = sb;
    }
}

// aggN stored in TRUE feature order.
__global__ __launch_bounds__(256) void packfrag_upd_kernel(
    const float* __restrict__ uW1, const float* __restrict__ M2U,
    const float* __restrict__ uW2, f16x8* __restrict__ updB)
{
    int t = blockIdx.x * 256 + threadIdx.x;  // 0..3071
    if (t >= 3072) return;
    int lane = t & 63;
    int frag = t >> 6;  // 0..47
    int l = frag / 24, f = frag % 24;
    int quad = lane >> 4, l15 = lane & 15;
    int g = f >> 3, ff = f & 7;
    int nt = ff >> 1, kk = ff & 1;
    const float* src;
    if (g == 0)      src = uW1 + (size_t)l * 8192;       // rows 0..63
    else if (g == 1) src = M2U + (size_t)l * 4096;
    else             src = uW2 + (size_t)l * 4096;
    f16x8 v;
#pragma unroll
    for (int j = 0; j < 8; ++j) {
        int k = kk * 32 + quad * 8 + j;
        v[j] = (_Float16)src[k * 64 + nt * 16 + l15];
    }
    updB[(size_t)frag * 64 + lane] = v;
}

// ----------------------------------------------- scan (M <= 256k) ---------
__global__ __launch_bounds__(256) void scan1_kernel(
    const int* __restrict__ deg, int* __restrict__ part,
    int* __restrict__ bsum, int N)
{
    __shared__ int lds[256];
    int t = threadIdx.x;
    int base = blockIdx.x * 1024 + t * 4;
    int v[4];
#pragma unroll
    for (int s = 0; s < 4; ++s) v[s] = (base + s < N) ? deg[base + s] : 0;
    int sum = v[0] + v[1] + v[2] + v[3];
    lds[t] = sum;
    __syncthreads();
    for (int off = 1; off < 256; off <<= 1) {
        int xv = (t >= off) ? lds[t - off] : 0;
        __syncthreads();
        lds[t] += xv;
        __syncthreads();
    }
    int excl = lds[t] - sum;
    if (t == 255) bsum[blockIdx.x] = lds[255];
    int p = excl;
#pragma unroll
    for (int s = 0; s < 4; ++s) {
        if (base + s < N) part[base + s] = p;
        p += v[s];
    }
}

__global__ __launch_bounds__(256) void scan2_kernel(int* __restrict__ bsum, int nb)
{
    __shared__ int lds[256];
    int t = threadIdx.x;
    int v = (t < nb) ? bsum[t] : 0;
    lds[t] = v;
    __syncthreads();
    for (int off = 1; off < 256; off <<= 1) {
        int xv = (t >= off) ? lds[t - off] : 0;
        __syncthreads();
        lds[t] += xv;
        __syncthreads();
    }
    if (t < nb) bsum[t] = lds[t] - v;
}

__global__ __launch_bounds__(256) void scan3_kernel(
    int* __restrict__ part, const int* __restrict__ bsum, int N)
{
    int i = blockIdx.x * 256 + threadIdx.x;
    if (i >= N) return;
    part[i] = part[i] + bsum[i >> 10];
}

// ----------------------------------------- coarse bucket partition --------
// R22: replaces direct atomic-cursor CSR scatter (place_csr: 100 MB HBM
// writes = 8x line amplification from random 8B stores, ~120us). Bucketed
// two-pass: place scatters into per-(bucket,block) CONTIGUOUS segments
// (avg 8 consecutive int2 = one full 64B line), bucket_sort then makes
// each bucket CSR-ordered with sequential R/W and emits deg/startp.
__global__ __launch_bounds__(256) void count_bucket_kernel(
    const int* __restrict__ col, int* __restrict__ cnt,
    int E, int NB, int NBK, int BS)
{
    __shared__ int lc[NBKT];
    int t = threadIdx.x;
    for (int i = t; i < NBK; i += 256) lc[i] = 0;
    __syncthreads();
    for (int s = 0; s < EPB / 256; ++s) {
        int e = blockIdx.x * EPB + s * 256 + t;
        if (e < E) atomicAdd(lc + (unsigned)col[e] / (unsigned)BS, 1);
    }
    __syncthreads();
    for (int i = t; i < NBK; i += 256)
        cnt[(size_t)i * NB + blockIdx.x] = lc[i];
}

// edata.x packs row | (local_col << 20)  (row < 2^20; local_col < BS <= 256)
__global__ __launch_bounds__(256) void place_kernel(
    const int* __restrict__ row, const int* __restrict__ col,
    const float* __restrict__ ew, const int* __restrict__ off,
    int2* __restrict__ edata, int E, int NB, int NBK, int BS)
{
    __shared__ int lc[NBKT];
    int t = threadIdx.x;
    for (int i = t; i < NBK; i += 256) lc[i] = 0;
    __syncthreads();
    for (int s = 0; s < EPB / 256; ++s) {
        int e = blockIdx.x * EPB + s * 256 + t;
        if (e < E) {
            int cv = col[e];
            int c = (unsigned)cv / (unsigned)BS;
            int lcol = cv - c * BS;
            int r = atomicAdd(lc + c, 1);
            int pos = off[(size_t)c * NB + blockIdx.x] + r;
            edata[pos] = make_int2(row[e] | (lcol << 20), __float_as_int(ew[e]));
        }
    }
}

// per-bucket in-place counting sort by local node; emits deg/startp.
__global__ __launch_bounds__(256) void bucket_sort_kernel(
    int2* __restrict__ edata, const int* __restrict__ off,
    int* __restrict__ deg, int* __restrict__ startp,
    int NB, int BS, int N, int E, int NBK)
{
    __shared__ int hist[256];
    __shared__ int psum[256];
    int b = blockIdx.x;
    int t = threadIdx.x;
    int base = off[(size_t)b * NB];
    int end  = (b + 1 < NBK) ? off[(size_t)(b + 1) * NB] : E;
    int cnt = end - base;
    int nlo = b * BS;

    hist[t] = 0;
    __syncthreads();

    int2 regs[8];
    int lnode[8];
#pragma unroll
    for (int ii = 0; ii < 8; ++ii) {
        int i = t + ii * 256;
        if (i < cnt) {
            regs[ii] = edata[base + i];
            lnode[ii] = ((unsigned)regs[ii].x) >> 20;
            atomicAdd(hist + lnode[ii], 1);   // no-return ds_add
        }
    }
    __syncthreads();

    int cv = hist[t];
    psum[t] = cv;
    __syncthreads();
    for (int o = 1; o < 256; o <<= 1) {
        int xv = (t >= o) ? psum[t - o] : 0;
        __syncthreads();
        psum[t] += xv;
        __syncthreads();
    }
    int excl = psum[t] - cv;
    int ng = nlo + t;
    if (t < BS && ng < N) {
        deg[ng] = cv;
        startp[ng] = base + excl;
    }
    hist[t] = excl;
    __syncthreads();

#pragma unroll
    for (int ii = 0; ii < 8; ++ii) {
        int i = t + ii * 256;
        if (i < cnt) {
            int pos = atomicAdd(hist + lnode[ii], 1);
            edata[base + pos] = make_int2(regs[ii].x & 0xFFFFF, regs[ii].y);
        }
    }
}

// -------------------------------------------------- per-node U/V GEMM -----
__global__ __launch_bounds__(256) void uv_mfma_kernel(
    const _Float16* __restrict__ xh, const f16x8* __restrict__ Bf,
    const float* __restrict__ mb1, const float* __restrict__ ab1,
    _Float16* __restrict__ out, int N, int side)
{
    int lane = threadIdx.x & 63;
    int wid = (blockIdx.x * 256 + threadIdx.x) >> 6;
    int quad = lane >> 4, l15 = lane & 15;
    int nbase = wid * 64;
    if (nbase >= N) return;

    f16x8 B[12];
#pragma unroll
    for (int i = 0; i < 12; ++i) B[i] = Bf[i * 64 + lane];
    float bv[6];
#pragma unroll
    for (int nt = 0; nt < 6; ++nt) {
        int col = nt * 16 + l15;
        bv[nt] = side ? 0.f : (col < 64 ? mb1[col] : ab1[col - 64]);
    }

    for (int mt = 0; mt < 4; ++mt) {
        int na = nbase + mt * 16 + l15;
        if (na >= N) na = N - 1;
        const f16x8* xrow = (const f16x8*)(xh + (size_t)na * H);
        f16x8 Ax[2];
        Ax[0] = xrow[quad];
        Ax[1] = xrow[4 + quad];

        f32x4 C[6];
#pragma unroll
        for (int nt = 0; nt < 6; ++nt) {
            f32x4 cc = {bv[nt], bv[nt], bv[nt], bv[nt]};
#pragma unroll
            for (int kk = 0; kk < 2; ++kk)
                cc = __builtin_amdgcn_mfma_f32_16x16x32_f16(Ax[kk], B[nt * 2 + kk], cc, 0, 0, 0);
            C[nt] = cc;
        }
#pragma unroll
        for (int r = 0; r < 4; ++r) {
            int n = nbase + mt * 16 + quad * 4 + r;
            if (n < N) {
#pragma unroll
                for (int nt = 0; nt < 6; ++nt)
                    out[(size_t)n * 96 + nt * 16 + l15] = (_Float16)C[nt][r];
            }
        }
    }
}

// ---------------------------------------------------------- edge gather ---
// Per-edge work is pure VALU: h = relu(U[row]+V[col]), att = sigmoid dot.
// One wave owns NPW nodes; 8 groups x 8 lanes process 8 edges of the
// current node, register accumulation, shfl_xor cross-group reduce.
__global__ __launch_bounds__(256) void edge_gather_kernel(
    const _Float16* __restrict__ Ur,   // [N][96]
    const _Float16* __restrict__ Vc,   // [N][96]
    const int2* __restrict__ edata,    // CSR-sorted {row, ew}
    const int* __restrict__ startp, const int* __restrict__ deg,
    const float* __restrict__ aW2, const float* __restrict__ ab2,
    _Float16* __restrict__ aggN, float* __restrict__ snorm, int N)
{
    int wid = (blockIdx.x * 256 + threadIdx.x) >> 6;
    int lane = threadIdx.x & 63;
    int g = lane >> 3, s = lane & 7;
    int n0 = wid * NPW;
    if (n0 >= N) return;
    int n1 = n0 + NPW; if (n1 > N) n1 = N;

    float aw2v[4];
#pragma unroll
    for (int j = 0; j < 4; ++j) aw2v[j] = aW2[s * 4 + j];
    float ab2v = ab2[0];

    for (int n = n0; n < n1; ++n) {
        int e0 = startp[n];
        int d = deg[n];
        const _Float16* vrow = Vc + (size_t)n * 96;
        f16x8 vm = *(const f16x8*)(vrow + s * 8);
        f16x4 va = *(const f16x4*)(vrow + 64 + s * 4);

        float acc[8];
#pragma unroll
        for (int j = 0; j < 8; ++j) acc[j] = 0.f;
        float rfw = 0.f;

        int iters = (d + 7) >> 3;
        for (int it = 0; it < iters; ++it) {
            int ei = it * 8 + g;
            bool valid = ei < d;
            int e = e0 + (valid ? ei : 0);
            int2 ed = edata[e];
            float ew = valid ? __int_as_float(ed.y) : 0.f;
            const _Float16* urow = Ur + (size_t)ed.x * 96;
            f16x8 um = *(const f16x8*)(urow + s * 8);
            f16x4 ua = *(const f16x4*)(urow + 64 + s * 4);

            _Float16 h[8];
#pragma unroll
            for (int j = 0; j < 8; ++j) {
                _Float16 z = um[j] + vm[j];
                h[j] = z > (_Float16)0 ? z : (_Float16)0;
            }
            float pp = 0.f;
#pragma unroll
            for (int j = 0; j < 4; ++j) {
                _Float16 za = ua[j] + va[j];
                float zf = (float)(za > (_Float16)0 ? za : (_Float16)0);
                pp += zf * aw2v[j];
            }
            pp += __shfl_xor(pp, 1);
            pp += __shfl_xor(pp, 2);
            pp += __shfl_xor(pp, 4);
            float fw = ew / (1.f + __expf(-(pp + ab2v)));
#pragma unroll
            for (int j = 0; j < 8; ++j) acc[j] += (float)h[j] * fw;
            rfw += fw;
        }

#pragma unroll
        for (int o = 8; o <= 32; o <<= 1) {
#pragma unroll
            for (int j = 0; j < 8; ++j) acc[j] += __shfl_xor(acc[j], o);
            rfw += __shfl_xor(rfw, o);
        }
        float inv = 1.f / fmaxf(rfw, 1e-6f);
        if (g == 0) {
            union { _Float16 h[8]; uint4 v; } O;
#pragma unroll
            for (int j = 0; j < 8; ++j) O.h[j] = (_Float16)(acc[j] * inv);
            *(uint4*)(aggN + (size_t)n * H + s * 8) = O.v;
        }
        if (lane == 0) snorm[n] = rfw * inv;
    }
}

// --------------------------------------------------------------- update ----
__global__ __launch_bounds__(256, 2) void update_mfma_kernel(
    _Float16* __restrict__ xh, const _Float16* __restrict__ agg,
    const float* __restrict__ snorm,
    const f16x8* __restrict__ Bfrag,  // [24][64] this layer
    const float* __restrict__ mbu,    // [64]
    const float* __restrict__ ub1, const float* __restrict__ ub2, int N)
{
    __shared__ __align__(16) _Float16 hlds[4][16 * 80];
    int wib = threadIdx.x >> 6;
    int lane = threadIdx.x & 63;
    int wid = (blockIdx.x * 256 + threadIdx.x) >> 6;
    int quad = lane >> 4, l15 = lane & 15;
    int nbase = wid * 64;
    if (nbase >= N) return;

    f16x8 Bu[8], Bm[8], Bw[8];
#pragma unroll
    for (int i = 0; i < 8; ++i) {
        Bu[i] = Bfrag[i * 64 + lane];
        Bm[i] = Bfrag[(8 + i) * 64 + lane];
        Bw[i] = Bfrag[(16 + i) * 64 + lane];
    }
    float mbuv[4], b1v[4], b2v[4];
#pragma unroll
    for (int nt = 0; nt < 4; ++nt) {
        mbuv[nt] = mbu[nt * 16 + l15];
        b1v[nt] = ub1[nt * 16 + l15];
        b2v[nt] = ub2[nt * 16 + l15];
    }

    for (int mt = 0; mt < 4; ++mt) {
        int na = nbase + mt * 16 + l15;
        if (na >= N) na = N - 1;
        const f16x8* xrow = (const f16x8*)(xh + (size_t)na * H);
        f16x8 Ax[2];
        Ax[0] = xrow[quad];
        Ax[1] = xrow[4 + quad];
        const f16x8* arow = (const f16x8*)(agg + (size_t)na * H);
        f16x8 Aa[2];
        Aa[0] = arow[quad];
        Aa[1] = arow[4 + quad];

        f32x4 Cx[4], Ca[4];
#pragma unroll
        for (int nt = 0; nt < 4; ++nt) {
            f32x4 cx = {0.f, 0.f, 0.f, 0.f}, ca = {0.f, 0.f, 0.f, 0.f};
#pragma unroll
            for (int kk = 0; kk < 2; ++kk) {
                cx = __builtin_amdgcn_mfma_f32_16x16x32_f16(Ax[kk], Bu[nt * 2 + kk], cx, 0, 0, 0);
                ca = __builtin_amdgcn_mfma_f32_16x16x32_f16(Aa[kk], Bm[nt * 2 + kk], ca, 0, 0, 0);
            }
            Cx[nt] = cx; Ca[nt] = ca;
        }

        int noder = nbase + mt * 16 + quad * 4;
        float sn_r[4];
#pragma unroll
        for (int r = 0; r < 4; ++r) {
            int ng = noder + r; if (ng >= N) ng = N - 1;
            sn_r[r] = snorm[ng];
        }

#pragma unroll
        for (int nt = 0; nt < 4; ++nt) {
#pragma unroll
            for (int r = 0; r < 4; ++r) {
                float hv = fmaxf(Cx[nt][r] + Ca[nt][r]
                                 + sn_r[r] * mbuv[nt] + b1v[nt], 0.f);
                hlds[wib][(quad * 4 + r) * 80 + nt * 16 + l15] = (_Float16)hv;
            }
        }
        __asm__ __volatile__("s_waitcnt lgkmcnt(0)" ::: "memory");
        f16x8 Ah[2];
        Ah[0] = *(const f16x8*)&hlds[wib][l15 * 80 + quad * 8];
        Ah[1] = *(const f16x8*)&hlds[wib][l15 * 80 + 32 + quad * 8];
        __asm__ __volatile__("s_waitcnt lgkmcnt(0)" ::: "memory");

        f32x4 C2[4];
#pragma unroll
        for (int nt = 0; nt < 4; ++nt) {
            f32x4 cc = {0.f, 0.f, 0.f, 0.f};
#pragma unroll
            for (int kk = 0; kk < 2; ++kk)
                cc = __builtin_amdgcn_mfma_f32_16x16x32_f16(Ah[kk], Bw[nt * 2 + kk], cc, 0, 0, 0);
            C2[nt] = cc;
        }

#pragma unroll
        for (int r = 0; r < 4; ++r) {
            int ng = noder + r;
            if (ng < N) {
#pragma unroll
                for (int nt = 0; nt < 4; ++nt) {
                    size_t idx = (size_t)ng * H + nt * 16 + l15;
                    float xo = (float)xh[idx];
                    xh[idx] = (_Float16)fmaxf(C2[nt][r] + b2v[nt] + xo, 0.f);
                }
            }
        }
    }
}

// ----------------------------------------------------------------- head ----
__global__ __launch_bounds__(256) void max_kernel(
    const _Float16* __restrict__ xh16, unsigned int* __restrict__ serp, int N)
{
    int j = threadIdx.x & (H - 1);
    int g = (blockIdx.x * 256 + threadIdx.x) >> 6;
    int stride = (gridDim.x * 256) >> 6;
    float m = 0.f;  // x >= 0 after relu
    for (int n = g; n < N; n += stride)
        m = fmaxf(m, (float)xh16[(size_t)n * H + j]);
    atomicMax(serp + j, __float_as_uint(m));
}

__global__ void head_kernel(const unsigned int* __restrict__ serp,
                            const float* __restrict__ hW,
                            const float* __restrict__ hb,
                            float* __restrict__ out)
{
    int j = threadIdx.x;  // 64 threads = 1 wave
    float v = __uint_as_float(serp[j]) * hW[j];
#pragma unroll
    for (int off = 32; off > 0; off >>= 1) v += __shfl_down(v, off);
    if (j == 0) out[0] = v + hb[0];
}

// --------------------------------------------------------------- launch ----
extern "C" void kernel_launch(void* const* d_in, const int* in_sizes, int n_in,
                              void* d_out, int out_size, void* d_ws, size_t ws_size,
                              hipStream_t stream)
{
    const float* nf  = (const float*)d_in[0];
    const int*   ei  = (const int*)d_in[1];
    const float* ew  = (const float*)d_in[2];
    const float* eW  = (const float*)d_in[3];
    const float* eb_ = (const float*)d_in[4];
    const float* mW1 = (const float*)d_in[5];
    const float* mb1 = (const float*)d_in[6];
    const float* mW2 = (const float*)d_in[7];
    const float* mb2 = (const float*)d_in[8];
    const float* aW1 = (const float*)d_in[9];
    const float* ab1 = (const float*)d_in[10];
    const float* aW2 = (const float*)d_in[11];
    const float* ab2 = (const float*)d_in[12];
    const float* uW1 = (const float*)d_in[13];
    const float* ub1 = (const float*)d_in[14];
    const float* uW2 = (const float*)d_in[15];
    const float* ub2 = (const float*)d_in[16];
    const float* hW  = (const float*)d_in[17];
    const float* hb  = (const float*)d_in[18];

    int N = in_sizes[0] / F;
    int E = in_sizes[2];
    const int* row = ei;
    const int* col = ei + E;

    size_t Nr = ((size_t)N + 3) & ~(size_t)3;
    size_t Er = ((size_t)E + 3) & ~(size_t)3;

    int BS  = (N + NBKT - 1) / NBKT;       // nodes per bucket (<=256)
    int NBK = (N + BS - 1) / BS;           // actual buckets (<=NBKT)
    int NB  = (E + EPB - 1) / EPB;         // blocks in count/place
    size_t M  = (size_t)NBK * NB;
    size_t Mr = (M + 3) & ~(size_t)3;

    _Float16* xh   = (_Float16*)d_ws;                 // Nr*64 f16
    _Float16* aggN = xh + Nr * 64;                    // Nr*64 f16
    float* snorm   = (float*)(aggN + Nr * 64);        // Nr
    unsigned int* serp = (unsigned int*)(snorm + Nr); // 64
    int* deg       = (int*)(serp + 64);               // Nr
    int* startp    = deg + Nr;                        // Nr
    int* bsum      = startp + Nr;                     // 256
    float* M2U     = (float*)(bsum + 256);            // 8192
    float* mbu     = M2U + 8192;                      // 128
    f16x8* updB    = (f16x8*)(mbu + 128);             // 3072 units
    f16x8* uvB     = updB + 3072;                     // 3072 units
    _Float16* Ur   = (_Float16*)(uvB + 3072);         // Nr*96
    _Float16* Vc   = Ur + Nr * 96;                    // Nr*96
    int* cnt       = (int*)(Vc + Nr * 96);            // Mr
    int* off       = cnt + Mr;                        // Mr
    int2* edata    = (int2*)(off + Mr);               // Er

    int nb_n = (N + 255) / 256;
    int nbA = (int)((M + 1023) / 1024);               // <=256

    count_bucket_kernel<<<NB, 256, 0, stream>>>(col, cnt, E, NB, NBK, BS);
    scan1_kernel<<<nbA, 256, 0, stream>>>(cnt, off, bsum, (int)M);
    scan2_kernel<<<1, 256, 0, stream>>>(bsum, nbA);
    scan3_kernel<<<(int)((M + 255) / 256), 256, 0, stream>>>(off, bsum, (int)M);
    place_kernel<<<NB, 256, 0, stream>>>(row, col, ew, off, edata, E, NB, NBK, BS);
    bucket_sort_kernel<<<NBK, 256, 0, stream>>>(edata, off, deg, startp,
                                                NB, BS, N, E, NBK);

    packfrag_uv_kernel<<<12, 256, 0, stream>>>(mW1, aW1, uvB);
    prep_update_kernel<<<32, 256, 0, stream>>>(mW2, mb2, uW1, M2U, mbu);
    packfrag_upd_kernel<<<12, 256, 0, stream>>>(uW1, M2U, uW2, updB);
    embed_kernel<<<nb_n, 256, 0, stream>>>(nf, eW, eb_, xh, N);

    int nwaves_n = (N + 63) / 64;
    int nb_uv = (N + 255) / 256;
    int nb_eg = (N + NPW * 4 - 1) / (NPW * 4);
    for (int l = 0; l < 2; ++l) {
        uv_mfma_kernel<<<nb_uv, 256, 0, stream>>>(
            xh, uvB + ((size_t)l * 2 + 0) * 12 * 64,
            mb1 + (size_t)l * H, ab1 + (size_t)l * (H / 2), Ur, N, 0);
        uv_mfma_kernel<<<nb_uv, 256, 0, stream>>>(
            xh, uvB + ((size_t)l * 2 + 1) * 12 * 64,
            mb1, ab1, Vc, N, 1);
        edge_gather_kernel<<<nb_eg, 256, 0, stream>>>(
            Ur, Vc, edata, startp, deg,
            aW2 + (size_t)l * (H / 2), ab2 + (size_t)l,
            aggN, snorm, N);
        update_mfma_kernel<<<(nwaves_n + 3) / 4, 256, 0, stream>>>(
            xh, aggN, snorm,
            updB + (size_t)l * 24 * 64,
            mbu + (size_t)l * 64,
            ub1 + (size_t)l * H, ub2 + (size_t)l * H, N);
    }

    hipMemsetAsync(serp, 0, 64 * sizeof(unsigned int), stream);
    max_kernel<<<256, 256, 0, stream>>>(xh, serp, N);
    head_kernel<<<1, 64, 0, stream>>>(serp, hW, hb, (float*)d_out);
}